// Round 1
// baseline (248.646 us; speedup 1.0000x reference)
//
#include <hip/hip_runtime.h>
#include <math.h>

#define B 4
#define C 64
#define H 64
#define W 64
#define HW 4096
#define NEG 256
#define CHUNK_P 32
#define NCHUNK (HW / CHUNK_P)   // 128

// ---------------- ws layout (floats) ----------------
// z2t    : [B][HW][64]          = 1048576
// n2map  : [B][HW]              = 16384
// n1map  : [B][HW]              = 16384
// imgt4  : [HW][4]              = 16384
// partial: [B][NCHUNK][NEG]     = 131072
// perb   : [B][3]               = 12
#define OFF_Z2T     0
#define OFF_N2MAP   (OFF_Z2T + B*HW*64)
#define OFF_N1MAP   (OFF_N2MAP + B*HW)
#define OFF_IMGT4   (OFF_N1MAP + B*HW)
#define OFF_PARTIAL (OFF_IMGT4 + HW*4)
#define OFF_PERB    (OFF_PARTIAL + B*NCHUNK*NEG)

// Transpose views_2 (C,HW) -> z2t (HW,C) per item, and compute per-pixel norms.
__global__ __launch_bounds__(256) void k_prep_z2(const float* __restrict__ v2,
                                                 float* __restrict__ z2t,
                                                 float* __restrict__ n2map) {
    __shared__ float tile[64][65];
    __shared__ float npart[4][64];
    int b  = blockIdx.x >> 6;          // 64 tiles per item
    int q0 = (blockIdx.x & 63) * 64;
    int t  = threadIdx.x;
    int qq = t & 63;
    int cg = t >> 6;
    const float* src = v2 + (size_t)b * C * HW;
    float acc = 0.f;
#pragma unroll
    for (int r = 0; r < 16; ++r) {
        int c = cg * 16 + r;
        float v = src[(size_t)c * HW + q0 + qq];
        tile[c][qq] = v;
        acc += v * v;
    }
    npart[cg][qq] = acc;
    __syncthreads();
    if (t < 64) {
        float s = npart[0][t] + npart[1][t] + npart[2][t] + npart[3][t];
        n2map[b * HW + q0 + t] = sqrtf(s);
    }
    int qw = t >> 2;
    int c0 = (t & 3) * 16;
    float* dst = z2t + ((size_t)(b * HW + q0 + qw)) * 64 + c0;
#pragma unroll
    for (int j = 0; j < 4; ++j) {
        float4 w4 = make_float4(tile[c0 + 4*j + 0][qw], tile[c0 + 4*j + 1][qw],
                                tile[c0 + 4*j + 2][qw], tile[c0 + 4*j + 3][qw]);
        *(float4*)(dst + 4 * j) = w4;
    }
}

// n1map (per-pixel norm of views_1) + img as float4 table.
__global__ __launch_bounds__(256) void k_prep_z1(const float* __restrict__ v1,
                                                 const float* __restrict__ img,
                                                 float* __restrict__ n1map,
                                                 float* __restrict__ imgt4) {
    int b = blockIdx.x >> 4;                       // 16 blocks of 256 per item
    int q = (blockIdx.x & 15) * 256 + threadIdx.x;
    const float* src = v1 + (size_t)b * C * HW + q;
    float acc = 0.f;
#pragma unroll 8
    for (int c = 0; c < C; ++c) {
        float v = src[(size_t)c * HW];
        acc += v * v;
    }
    n1map[b * HW + q] = sqrtf(acc);
    if (b == 0) {
        float4 ip = make_float4(img[q], img[HW + q], img[2 * HW + q], 0.f);
        *(float4*)(imgt4 + q * 4) = ip;
    }
}

// Main: block handles (b, 32 pixels); thread = one k. Accumulates sim over the 32 p's.
__global__ __launch_bounds__(256) void k_main(const float* __restrict__ v1,
                                              const int* __restrict__ negh,
                                              const int* __restrict__ negw,
                                              const float* __restrict__ z2t,
                                              const float* __restrict__ n2map,
                                              const float* __restrict__ n1map,
                                              const float* __restrict__ imgt4,
                                              float* __restrict__ partial) {
    __shared__ __align__(16) float z1s[CHUNK_P][64];
    __shared__ float n1s[CHUNK_P];
    __shared__ float4 imgps[CHUNK_P];
    int b     = blockIdx.x >> 7;       // NCHUNK = 128
    int chunk = blockIdx.x & 127;
    int p0    = chunk * CHUNK_P;
    int t     = threadIdx.x;

    {   // stage z1 columns for the 32 pixels: z1s[pp][c]
        int c   = t >> 2;
        int pp0 = (t & 3) * 8;
        const float* src = v1 + (size_t)b * C * HW + (size_t)c * HW + p0 + pp0;
#pragma unroll
        for (int j = 0; j < 8; ++j) z1s[pp0 + j][c] = src[j];
    }
    if (t < CHUNK_P) {
        n1s[t]   = n1map[b * HW + p0 + t];
        imgps[t] = *(const float4*)(imgt4 + (p0 + t) * 4);
    }
    __syncthreads();

    const float inv_max_euc = 1.0f / sqrtf((float)((H - 1) * (H - 1) + (W - 1) * (W - 1)));
    const float inv_sqrt3   = 0.57735026919f;
    const float* z2b = z2t + (size_t)b * HW * 64;
    const int* nh = negh + ((size_t)b * HW + p0) * NEG + t;
    const int* nw = negw + ((size_t)b * HW + p0) * NEG + t;

    float acc = 0.f;
    for (int pp = 0; pp < CHUNK_P; ++pp) {
        int p = p0 + pp;
        float hp = (float)(p >> 6);
        float wp = (float)(p & 63);
        int ih = nh[pp * NEG];
        int iw = nw[pp * NEG];
        int q  = (ih << 6) + iw;
        float n2q = n2map[b * HW + q];
        const float4* zc  = (const float4*)(z2b + (size_t)q * 64);
        const float4* z1c = (const float4*)(&z1s[pp][0]);   // wave-uniform -> LDS broadcast
        float4 d4 = make_float4(0.f, 0.f, 0.f, 0.f);
#pragma unroll
        for (int j = 0; j < 16; ++j) {
            float4 a  = zc[j];
            float4 zz = z1c[j];
            d4.x += a.x * zz.x; d4.y += a.y * zz.y;
            d4.z += a.z * zz.z; d4.w += a.w * zz.w;
        }
        float dot = (d4.x + d4.y) + (d4.z + d4.w);
        float cosv = dot / fmaxf(n1s[pp] * n2q, 1e-8f);
        float dh = hp - (float)ih, dw = wp - (float)iw;
        float euc = sqrtf(dh * dh + dw * dw) * inv_max_euc;
        float4 iq = *(const float4*)(imgt4 + q * 4);
        float4 ip = imgps[pp];
        float dr = ip.x - iq.x, dg = ip.y - iq.y, db = ip.z - iq.z;
        float rgb = sqrtf(dr * dr + dg * dg + db * db) * inv_sqrt3;
        float wgt = 0.8f * euc + 0.2f * rgb;
        acc += fminf(fabsf(cosv * wgt), 1.0f);
    }
    partial[((size_t)b * NCHUNK + chunk) * NEG + t] = acc;
}

// Per-item reduction: sneg[k], log terms, s0, bce.
__global__ __launch_bounds__(256) void k_reduce(const float* __restrict__ partial,
                                                const float* __restrict__ n1map,
                                                float* __restrict__ perb) {
    __shared__ float red[256];
    int b = blockIdx.x;
    int t = threadIdx.x;
    float s = 0.f;
    for (int ch = 0; ch < NCHUNK; ++ch)
        s += partial[((size_t)b * NCHUNK + ch) * NEG + t];
    float sneg = s * (1.0f / HW) * 0.5f;                 // / HW / TEMPERATURE
    float l1m  = fmaxf(logf(1.0f - sneg), -100.0f);
    float ss = 0.f;
#pragma unroll
    for (int j = 0; j < HW / 256; ++j) {
        float n1 = n1map[b * HW + j * 256 + t];
        float n1sq = n1 * n1;
        ss += fminf(n1sq / fmaxf(n1sq, 1e-8f), 1.0f);
    }
    float snegsum, l1msum, sssum;
    red[t] = sneg; __syncthreads();
    for (int sft = 128; sft > 0; sft >>= 1) { if (t < sft) red[t] += red[t + sft]; __syncthreads(); }
    snegsum = red[0]; __syncthreads();
    red[t] = l1m; __syncthreads();
    for (int sft = 128; sft > 0; sft >>= 1) { if (t < sft) red[t] += red[t + sft]; __syncthreads(); }
    l1msum = red[0]; __syncthreads();
    red[t] = ss; __syncthreads();
    for (int sft = 128; sft > 0; sft >>= 1) { if (t < sft) red[t] += red[t + sft]; __syncthreads(); }
    sssum = red[0];
    if (t == 0) {
        float s0  = sssum * (1.0f / HW);
        float bce = -(fmaxf(logf(s0), -100.0f) + l1msum) * (1.0f / (NEG + 1));
        perb[b * 3 + 0] = bce;
        perb[b * 3 + 1] = s0;
        perb[b * 3 + 2] = snegsum;
    }
}

__global__ void k_final(const float* __restrict__ perb, float* __restrict__ out) {
    if (threadIdx.x == 0 && blockIdx.x == 0) {
        float bsum = 0.f, s0sum = 0.f, snegsum = 0.f;
        for (int b = 0; b < B; ++b) {
            bsum    += perb[b * 3 + 0];
            s0sum   += perb[b * 3 + 1];
            snegsum += perb[b * 3 + 2];
        }
        out[0] = bsum * 0.25f;                              // mean bce
        out[1] = s0sum * 0.25f;                             // sim_all[0] / B
        out[2] = snegsum * (1.0f / NEG) * 2.0f * 0.25f;     // sum/NEG*TEMP/B
    }
}

extern "C" void kernel_launch(void* const* d_in, const int* in_sizes, int n_in,
                              void* d_out, int out_size, void* d_ws, size_t ws_size,
                              hipStream_t stream) {
    const float* v1   = (const float*)d_in[0];
    const float* v2   = (const float*)d_in[1];
    const float* img  = (const float*)d_in[2];
    const int*   negh = (const int*)d_in[3];
    const int*   negw = (const int*)d_in[4];
    float* out = (float*)d_out;
    float* ws  = (float*)d_ws;

    float* z2t     = ws + OFF_Z2T;
    float* n2map   = ws + OFF_N2MAP;
    float* n1map   = ws + OFF_N1MAP;
    float* imgt4   = ws + OFF_IMGT4;
    float* partial = ws + OFF_PARTIAL;
    float* perb    = ws + OFF_PERB;

    hipLaunchKernelGGL(k_prep_z2, dim3(B * 64), dim3(256), 0, stream, v2, z2t, n2map);
    hipLaunchKernelGGL(k_prep_z1, dim3(B * 16), dim3(256), 0, stream, v1, img, n1map, imgt4);
    hipLaunchKernelGGL(k_main, dim3(B * NCHUNK), dim3(256), 0, stream,
                       v1, negh, negw, z2t, n2map, n1map, imgt4, partial);
    hipLaunchKernelGGL(k_reduce, dim3(B), dim3(256), 0, stream, partial, n1map, perb);
    hipLaunchKernelGGL(k_final, dim3(1), dim3(64), 0, stream, perb, out);
}

// Round 2
// 154.714 us; speedup vs baseline: 1.6071x; 1.6071x over previous
//
#include <hip/hip_runtime.h>
#include <math.h>

#define B 4
#define C 64
#define H 64
#define W 64
#define HW 4096
#define NEG 256
#define CHUNK_P 8
#define NCHUNK (HW / CHUNK_P)   // 512
#define NGRP 16
#define CHPG (NCHUNK / NGRP)    // 32 chunks per reduce group

// ---------------- ws layout (floats) ----------------
// z2t     : [B][HW][64]  (pre-normalized by 1/n2) = 1048576
// n1map   : [B][HW]                               = 16384
// imgt4   : [HW][4]                               = 16384
// partial : [B][NCHUNK][NEG]                      = 524288
// partial2: [B][NGRP][NEG]                        = 16384
// perb    : [B][3]
#define OFF_Z2T     0
#define OFF_N1MAP   (OFF_Z2T + B*HW*64)
#define OFF_IMGT4   (OFF_N1MAP + B*HW)
#define OFF_PARTIAL (OFF_IMGT4 + HW*4)
#define OFF_PART2   (OFF_PARTIAL + B*NCHUNK*NEG)
#define OFF_PERB    (OFF_PART2 + B*NGRP*NEG)

// Transpose views_2 (C,HW) -> z2t (HW,C), columns pre-divided by their norm.
__global__ __launch_bounds__(256) void k_prep_z2(const float* __restrict__ v2,
                                                 float* __restrict__ z2t) {
    __shared__ float tile[64][65];
    __shared__ float npart[4][64];
    __shared__ float ninv[64];
    int b  = blockIdx.x >> 6;          // 64 tiles per item
    int q0 = (blockIdx.x & 63) * 64;
    int t  = threadIdx.x;
    int qq = t & 63;
    int cg = t >> 6;
    const float* src = v2 + (size_t)b * C * HW;
    float acc = 0.f;
#pragma unroll
    for (int r = 0; r < 16; ++r) {
        int c = cg * 16 + r;
        float v = src[(size_t)c * HW + q0 + qq];
        tile[c][qq] = v;
        acc += v * v;
    }
    npart[cg][qq] = acc;
    __syncthreads();
    if (t < 64) {
        float s = npart[0][t] + npart[1][t] + npart[2][t] + npart[3][t];
        ninv[t] = 1.0f / fmaxf(sqrtf(s), 1e-8f);
    }
    __syncthreads();
    int qw = t >> 2;
    int c0 = (t & 3) * 16;
    float inv = ninv[qw];
    float* dst = z2t + ((size_t)(b * HW + q0 + qw)) * 64 + c0;
#pragma unroll
    for (int j = 0; j < 4; ++j) {
        float4 w4 = make_float4(tile[c0 + 4*j + 0][qw] * inv, tile[c0 + 4*j + 1][qw] * inv,
                                tile[c0 + 4*j + 2][qw] * inv, tile[c0 + 4*j + 3][qw] * inv);
        *(float4*)(dst + 4 * j) = w4;
    }
}

// n1map (per-pixel norm of views_1) + img as float4 table.
__global__ __launch_bounds__(256) void k_prep_z1(const float* __restrict__ v1,
                                                 const float* __restrict__ img,
                                                 float* __restrict__ n1map,
                                                 float* __restrict__ imgt4) {
    int b = blockIdx.x >> 4;                       // 16 blocks of 256 per item
    int q = (blockIdx.x & 15) * 256 + threadIdx.x;
    const float* src = v1 + (size_t)b * C * HW + q;
    float acc = 0.f;
#pragma unroll 8
    for (int c = 0; c < C; ++c) {
        float v = src[(size_t)c * HW];
        acc += v * v;
    }
    n1map[b * HW + q] = sqrtf(acc);
    if (b == 0) {
        float4 ip = make_float4(img[q], img[HW + q], img[2 * HW + q], 0.f);
        *(float4*)(imgt4 + q * 4) = ip;
    }
}

// Main: block = (b, 8 pixels); thread = one k.
__global__ __launch_bounds__(256) void k_main(const float* __restrict__ v1,
                                              const int* __restrict__ negh,
                                              const int* __restrict__ negw,
                                              const float* __restrict__ z2t,
                                              const float* __restrict__ n1map,
                                              const float* __restrict__ imgt4,
                                              float* __restrict__ partial) {
    __shared__ __align__(16) float z1s[CHUNK_P][68];   // +4 pad: conflict-free staging
    __shared__ float4 imgps[CHUNK_P];
    int b     = blockIdx.x >> 9;       // NCHUNK = 512
    int chunk = blockIdx.x & 511;
    int p0    = chunk * CHUNK_P;
    int t     = threadIdx.x;

    {   // stage z1 columns, normalized: z1s[pp][c] = v1[c][p0+pp] / n1
        int c  = t >> 3;               // 0..31
        int pp = t & 7;
        const float* srcb = v1 + (size_t)b * C * HW;
        float inv = 1.0f / fmaxf(n1map[b * HW + p0 + pp], 1e-8f);
        z1s[pp][c]      = srcb[(size_t)c * HW        + p0 + pp] * inv;
        z1s[pp][c + 32] = srcb[(size_t)(c + 32) * HW + p0 + pp] * inv;
    }
    if (t < CHUNK_P) imgps[t] = *(const float4*)(imgt4 + (p0 + t) * 4);
    __syncthreads();

    const float inv_max_euc = 1.0f / sqrtf((float)((H - 1) * (H - 1) + (W - 1) * (W - 1)));
    const float inv_sqrt3   = 0.57735026919f;
    const float* z2b = z2t + (size_t)b * HW * 64;
    const int* nh = negh + ((size_t)b * HW + p0) * NEG + t;
    const int* nw = negw + ((size_t)b * HW + p0) * NEG + t;

    int   q[CHUNK_P];
    float wgt[CHUNK_P];
#pragma unroll
    for (int pp = 0; pp < CHUNK_P; ++pp) {
        int p = p0 + pp;
        int ih = nh[pp * NEG];
        int iw = nw[pp * NEG];
        q[pp] = (ih << 6) + iw;
        float dh = (float)(p >> 6) - (float)ih;
        float dw = (float)(p & 63) - (float)iw;
        float euc = sqrtf(dh * dh + dw * dw) * inv_max_euc;
        float4 iq = *(const float4*)(imgt4 + q[pp] * 4);
        float4 ip = imgps[pp];
        float dr = ip.x - iq.x, dg = ip.y - iq.y, db = ip.z - iq.z;
        float rgb = sqrtf(dr * dr + dg * dg + db * db) * inv_sqrt3;
        wgt[pp] = 0.8f * euc + 0.2f * rgb;
    }

    float acc = 0.f;
#pragma unroll 2
    for (int pp = 0; pp < CHUNK_P; ++pp) {
        const float4* zc  = (const float4*)(z2b + (size_t)q[pp] * 64);
        const float4* z1c = (const float4*)(&z1s[pp][0]);   // wave-uniform -> LDS broadcast
        float4 d4 = make_float4(0.f, 0.f, 0.f, 0.f);
#pragma unroll
        for (int j = 0; j < 16; ++j) {
            float4 a  = zc[j];
            float4 zz = z1c[j];
            d4.x += a.x * zz.x; d4.y += a.y * zz.y;
            d4.z += a.z * zz.z; d4.w += a.w * zz.w;
        }
        float cosv = (d4.x + d4.y) + (d4.z + d4.w);   // both sides pre-normalized
        acc += fminf(fabsf(cosv * wgt[pp]), 1.0f);
    }
    partial[((size_t)b * NCHUNK + chunk) * NEG + t] = acc;
}

// Stage-1 reduce: sum 32 chunks per group.
__global__ __launch_bounds__(256) void k_reduce1(const float* __restrict__ partial,
                                                 float* __restrict__ partial2) {
    int b = blockIdx.x >> 4;
    int g = blockIdx.x & 15;
    int t = threadIdx.x;
    float s = 0.f;
#pragma unroll 4
    for (int ch = 0; ch < CHPG; ++ch)
        s += partial[((size_t)b * NCHUNK + g * CHPG + ch) * NEG + t];
    partial2[((size_t)b * NGRP + g) * NEG + t] = s;
}

// Stage-2: per-item sneg[k], log terms, s0, bce.
__global__ __launch_bounds__(256) void k_reduce2(const float* __restrict__ partial2,
                                                 const float* __restrict__ n1map,
                                                 float* __restrict__ perb) {
    __shared__ float red[256];
    int b = blockIdx.x;
    int t = threadIdx.x;
    float s = 0.f;
#pragma unroll
    for (int g = 0; g < NGRP; ++g)
        s += partial2[((size_t)b * NGRP + g) * NEG + t];
    float sneg = s * (1.0f / HW) * 0.5f;                 // / HW / TEMPERATURE
    float l1m  = fmaxf(logf(1.0f - sneg), -100.0f);
    float ss = 0.f;
#pragma unroll
    for (int j = 0; j < HW / 256; ++j) {
        float n1 = n1map[b * HW + j * 256 + t];
        float n1sq = n1 * n1;
        ss += fminf(n1sq / fmaxf(n1sq, 1e-8f), 1.0f);
    }
    float snegsum, l1msum, sssum;
    red[t] = sneg; __syncthreads();
    for (int sft = 128; sft > 0; sft >>= 1) { if (t < sft) red[t] += red[t + sft]; __syncthreads(); }
    snegsum = red[0]; __syncthreads();
    red[t] = l1m; __syncthreads();
    for (int sft = 128; sft > 0; sft >>= 1) { if (t < sft) red[t] += red[t + sft]; __syncthreads(); }
    l1msum = red[0]; __syncthreads();
    red[t] = ss; __syncthreads();
    for (int sft = 128; sft > 0; sft >>= 1) { if (t < sft) red[t] += red[t + sft]; __syncthreads(); }
    sssum = red[0];
    if (t == 0) {
        float s0  = sssum * (1.0f / HW);
        float bce = -(fmaxf(logf(s0), -100.0f) + l1msum) * (1.0f / (NEG + 1));
        perb[b * 3 + 0] = bce;
        perb[b * 3 + 1] = s0;
        perb[b * 3 + 2] = snegsum;
    }
}

__global__ void k_final(const float* __restrict__ perb, float* __restrict__ out) {
    if (threadIdx.x == 0 && blockIdx.x == 0) {
        float bsum = 0.f, s0sum = 0.f, snegsum = 0.f;
        for (int b = 0; b < B; ++b) {
            bsum    += perb[b * 3 + 0];
            s0sum   += perb[b * 3 + 1];
            snegsum += perb[b * 3 + 2];
        }
        out[0] = bsum * 0.25f;                              // mean bce
        out[1] = s0sum * 0.25f;                             // sim_all[0] / B
        out[2] = snegsum * (1.0f / NEG) * 2.0f * 0.25f;     // sum/NEG*TEMP/B
    }
}

extern "C" void kernel_launch(void* const* d_in, const int* in_sizes, int n_in,
                              void* d_out, int out_size, void* d_ws, size_t ws_size,
                              hipStream_t stream) {
    const float* v1   = (const float*)d_in[0];
    const float* v2   = (const float*)d_in[1];
    const float* img  = (const float*)d_in[2];
    const int*   negh = (const int*)d_in[3];
    const int*   negw = (const int*)d_in[4];
    float* out = (float*)d_out;
    float* ws  = (float*)d_ws;

    float* z2t      = ws + OFF_Z2T;
    float* n1map    = ws + OFF_N1MAP;
    float* imgt4    = ws + OFF_IMGT4;
    float* partial  = ws + OFF_PARTIAL;
    float* partial2 = ws + OFF_PART2;
    float* perb     = ws + OFF_PERB;

    hipLaunchKernelGGL(k_prep_z2, dim3(B * 64), dim3(256), 0, stream, v2, z2t);
    hipLaunchKernelGGL(k_prep_z1, dim3(B * 16), dim3(256), 0, stream, v1, img, n1map, imgt4);
    hipLaunchKernelGGL(k_main, dim3(B * NCHUNK), dim3(256), 0, stream,
                       v1, negh, negw, z2t, n1map, imgt4, partial);
    hipLaunchKernelGGL(k_reduce1, dim3(B * NGRP), dim3(256), 0, stream, partial, partial2);
    hipLaunchKernelGGL(k_reduce2, dim3(B), dim3(256), 0, stream, partial2, n1map, perb);
    hipLaunchKernelGGL(k_final, dim3(1), dim3(64), 0, stream, perb, out);
}

// Round 4
// 62.530 us; speedup vs baseline: 3.9764x; 2.4742x over previous
//
#include <hip/hip_runtime.h>
#include <math.h>

typedef unsigned short ushort;
typedef unsigned int uint;

#define B 4
#define C 64
#define H 64
#define W 64
#define HW 4096
#define NEG 256
#define CHUNK_P 8
#define NCHUNK (HW / CHUNK_P)   // 512
#define NGRP 16
#define CHPG (NCHUNK / NGRP)    // 32

// ---------------- ws layout (float units) ----------------
// z2tb   : [B][HW][64] bf16 (column pre-normalized) = B*HW*32 floats
// n1map  : [B][HW]
// imgt4  : [HW][4]
// partial: [B][NCHUNK][NEG]
// partial2:[B][NGRP][NEG]
// perb   : [B][3]
#define OFF_Z2T     0
#define OFF_N1MAP   (OFF_Z2T + B*HW*32)
#define OFF_IMGT4   (OFF_N1MAP + B*HW)
#define OFF_PARTIAL (OFF_IMGT4 + HW*4)
#define OFF_PART2   (OFF_PARTIAL + B*NCHUNK*NEG)
#define OFF_PERB    (OFF_PART2 + B*NGRP*NEG)

__device__ __forceinline__ float blo(uint u) { return __uint_as_float(u << 16); }
__device__ __forceinline__ float bhi(uint u) { return __uint_as_float(u & 0xffff0000u); }

// f32 -> bf16 bits, round-to-nearest-even (finite inputs).
__device__ __forceinline__ uint f2bf(float f) {
    uint u = __float_as_uint(f);
    return (u + 0x7fffu + ((u >> 16) & 1u)) >> 16;
}

// Transpose views_2 (C,HW) -> z2tb (HW,C) bf16, columns pre-divided by their norm.
__global__ __launch_bounds__(256) void k_prep_z2(const float* __restrict__ v2,
                                                 ushort* __restrict__ z2tb) {
    __shared__ float tile[64][65];
    __shared__ float npart[4][64];
    __shared__ float ninv[64];
    int b  = blockIdx.x >> 6;          // 64 tiles per item
    int q0 = (blockIdx.x & 63) * 64;
    int t  = threadIdx.x;
    int qq = t & 63;
    int cg = t >> 6;
    const float* src = v2 + (size_t)b * C * HW;
    float acc = 0.f;
#pragma unroll
    for (int r = 0; r < 16; ++r) {
        int c = cg * 16 + r;
        float v = src[(size_t)c * HW + q0 + qq];
        tile[c][qq] = v;
        acc += v * v;
    }
    npart[cg][qq] = acc;
    __syncthreads();
    if (t < 64) {
        float s = npart[0][t] + npart[1][t] + npart[2][t] + npart[3][t];
        ninv[t] = 1.0f / fmaxf(sqrtf(s), 1e-8f);
    }
    __syncthreads();
    int qw = t >> 2;
    int c0 = (t & 3) * 16;
    float inv = ninv[qw];
    uint us[16];
#pragma unroll
    for (int j = 0; j < 16; ++j)
        us[j] = f2bf(tile[c0 + j][qw] * inv);
    uint4 w0, w1;
    w0.x = us[0]  | (us[1]  << 16); w0.y = us[2]  | (us[3]  << 16);
    w0.z = us[4]  | (us[5]  << 16); w0.w = us[6]  | (us[7]  << 16);
    w1.x = us[8]  | (us[9]  << 16); w1.y = us[10] | (us[11] << 16);
    w1.z = us[12] | (us[13] << 16); w1.w = us[14] | (us[15] << 16);
    uint4* dst = (uint4*)(z2tb + ((size_t)(b * HW + q0 + qw)) * 64 + c0);
    dst[0] = w0;
    dst[1] = w1;
}

// n1map (per-pixel norm of views_1) + img as float4 table.
__global__ __launch_bounds__(256) void k_prep_z1(const float* __restrict__ v1,
                                                 const float* __restrict__ img,
                                                 float* __restrict__ n1map,
                                                 float* __restrict__ imgt4) {
    int b = blockIdx.x >> 4;
    int q = (blockIdx.x & 15) * 256 + threadIdx.x;
    const float* src = v1 + (size_t)b * C * HW + q;
    float acc = 0.f;
#pragma unroll 8
    for (int c = 0; c < C; ++c) {
        float v = src[(size_t)c * HW];
        acc += v * v;
    }
    n1map[b * HW + q] = sqrtf(acc);
    if (b == 0) {
        float4 ip = make_float4(img[q], img[HW + q], img[2 * HW + q], 0.f);
        *(float4*)(imgt4 + q * 4) = ip;
    }
}

// Main: block = (b, 8 pixels). Phase A: q/wgt per (pp,k) into LDS (t=k).
// Phase B: 4-lane cooperative bf16 column gather; shfl-reduced dot.
__global__ __launch_bounds__(256) void k_main(const float* __restrict__ v1,
                                              const int* __restrict__ negh,
                                              const int* __restrict__ negw,
                                              const ushort* __restrict__ z2tb,
                                              const float* __restrict__ n1map,
                                              const float* __restrict__ imgt4,
                                              float* __restrict__ partial) {
    __shared__ __align__(16) float z1s[CHUNK_P][68];   // 68: row stride 272B (16B-mult)
    __shared__ float4 imgps[CHUNK_P];
    __shared__ int   q_lds[CHUNK_P][NEG];
    __shared__ float w_lds[CHUNK_P][NEG];
    int b     = blockIdx.x >> 9;       // NCHUNK = 512
    int chunk = blockIdx.x & 511;
    int p0    = chunk * CHUNK_P;
    int t     = threadIdx.x;

    {   // stage z1 columns, normalized: z1s[pp][c] = v1[c][p0+pp] / n1
        int c  = t >> 3;               // 0..31
        int pp = t & 7;
        const float* srcb = v1 + (size_t)b * C * HW;
        float inv = 1.0f / fmaxf(n1map[b * HW + p0 + pp], 1e-8f);
        z1s[pp][c]      = srcb[(size_t)c * HW        + p0 + pp] * inv;
        z1s[pp][c + 32] = srcb[(size_t)(c + 32) * HW + p0 + pp] * inv;
    }
    if (t < CHUNK_P) imgps[t] = *(const float4*)(imgt4 + (p0 + t) * 4);
    __syncthreads();

    const float inv_max_euc = 1.0f / sqrtf((float)((H - 1) * (H - 1) + (W - 1) * (W - 1)));
    const float inv_sqrt3   = 0.57735026919f;
    const int* nh = negh + ((size_t)b * HW + p0) * NEG + t;
    const int* nw = negw + ((size_t)b * HW + p0) * NEG + t;

    // Phase A: thread t = k index
#pragma unroll
    for (int pp = 0; pp < CHUNK_P; ++pp) {
        int p = p0 + pp;
        int ih = nh[pp * NEG];
        int iw = nw[pp * NEG];
        int qv = (ih << 6) + iw;
        float dh = (float)(p >> 6) - (float)ih;
        float dw = (float)(p & 63) - (float)iw;
        float euc = sqrtf(dh * dh + dw * dw) * inv_max_euc;
        float4 iq = *(const float4*)(imgt4 + qv * 4);
        float4 ip = imgps[pp];
        float dr = ip.x - iq.x, dg = ip.y - iq.y, db = ip.z - iq.z;
        float rgb = sqrtf(dr * dr + dg * dg + db * db) * inv_sqrt3;
        q_lds[pp][t] = qv;
        w_lds[pp][t] = 0.8f * euc + 0.2f * rgb;
    }
    __syncthreads();

    // Phase B: 4 lanes per column
    int c4 = t & 3;
    int kk = t >> 2;                   // 0..63 across block
    const ushort* z2b = z2tb + (size_t)b * HW * 64;
    float acc = 0.f;
#pragma unroll 1
    for (int pp = 0; pp < CHUNK_P; ++pp) {
        const float4* z1c = (const float4*)(&z1s[pp][0]);
        float4 u0 = z1c[2 * c4];
        float4 u1 = z1c[2 * c4 + 1];
        float4 u2 = z1c[8 + 2 * c4];
        float4 u3 = z1c[9 + 2 * c4];
#pragma unroll 2
        for (int g = 0; g < 4; ++g) {
            int kq = (g << 6) + kk;
            int qv = q_lds[pp][kq];
            float wv = w_lds[pp][kq];
            const uint4* col = (const uint4*)(z2b + (size_t)qv * 64);
            uint4 A = col[c4];         // channels 8c4..8c4+7   (bytes c4*16 of line 0)
            uint4 Bv = col[4 + c4];    // channels 32+8c4..+7   (line 1)
            float dot =
                blo(A.x)  * u0.x + bhi(A.x)  * u0.y +
                blo(A.y)  * u0.z + bhi(A.y)  * u0.w +
                blo(A.z)  * u1.x + bhi(A.z)  * u1.y +
                blo(A.w)  * u1.z + bhi(A.w)  * u1.w +
                blo(Bv.x) * u2.x + bhi(Bv.x) * u2.y +
                blo(Bv.y) * u2.z + bhi(Bv.y) * u2.w +
                blo(Bv.z) * u3.x + bhi(Bv.z) * u3.y +
                blo(Bv.w) * u3.z + bhi(Bv.w) * u3.w;
            dot += __shfl_xor(dot, 1);
            dot += __shfl_xor(dot, 2);
            float s = fminf(fabsf(dot * wv), 1.0f);
            acc += (g == c4) ? s : 0.f;
        }
    }
    partial[((size_t)b * NCHUNK + chunk) * NEG + (c4 << 6) + kk] = acc;
}

// Stage-1 reduce: sum 32 chunks per group.
__global__ __launch_bounds__(256) void k_reduce1(const float* __restrict__ partial,
                                                 float* __restrict__ partial2) {
    int b = blockIdx.x >> 4;
    int g = blockIdx.x & 15;
    int t = threadIdx.x;
    float s = 0.f;
#pragma unroll 4
    for (int ch = 0; ch < CHPG; ++ch)
        s += partial[((size_t)b * NCHUNK + g * CHPG + ch) * NEG + t];
    partial2[((size_t)b * NGRP + g) * NEG + t] = s;
}

// Stage-2: per-item sneg[k], log terms, s0, bce.
__global__ __launch_bounds__(256) void k_reduce2(const float* __restrict__ partial2,
                                                 const float* __restrict__ n1map,
                                                 float* __restrict__ perb) {
    __shared__ float red[256];
    int b = blockIdx.x;
    int t = threadIdx.x;
    float s = 0.f;
#pragma unroll
    for (int g = 0; g < NGRP; ++g)
        s += partial2[((size_t)b * NGRP + g) * NEG + t];
    float sneg = s * (1.0f / HW) * 0.5f;
    float l1m  = fmaxf(logf(1.0f - sneg), -100.0f);
    float ss = 0.f;
#pragma unroll
    for (int j = 0; j < HW / 256; ++j) {
        float n1 = n1map[b * HW + j * 256 + t];
        float n1sq = n1 * n1;
        ss += fminf(n1sq / fmaxf(n1sq, 1e-8f), 1.0f);
    }
    float snegsum, l1msum, sssum;
    red[t] = sneg; __syncthreads();
    for (int sft = 128; sft > 0; sft >>= 1) { if (t < sft) red[t] += red[t + sft]; __syncthreads(); }
    snegsum = red[0]; __syncthreads();
    red[t] = l1m; __syncthreads();
    for (int sft = 128; sft > 0; sft >>= 1) { if (t < sft) red[t] += red[t + sft]; __syncthreads(); }
    l1msum = red[0]; __syncthreads();
    red[t] = ss; __syncthreads();
    for (int sft = 128; sft > 0; sft >>= 1) { if (t < sft) red[t] += red[t + sft]; __syncthreads(); }
    sssum = red[0];
    if (t == 0) {
        float s0  = sssum * (1.0f / HW);
        float bce = -(fmaxf(logf(s0), -100.0f) + l1msum) * (1.0f / (NEG + 1));
        perb[b * 3 + 0] = bce;
        perb[b * 3 + 1] = s0;
        perb[b * 3 + 2] = snegsum;
    }
}

__global__ void k_final(const float* __restrict__ perb, float* __restrict__ out) {
    if (threadIdx.x == 0 && blockIdx.x == 0) {
        float bsum = 0.f, s0sum = 0.f, snegsum = 0.f;
        for (int b = 0; b < B; ++b) {
            bsum    += perb[b * 3 + 0];
            s0sum   += perb[b * 3 + 1];
            snegsum += perb[b * 3 + 2];
        }
        out[0] = bsum * 0.25f;
        out[1] = s0sum * 0.25f;
        out[2] = snegsum * (1.0f / NEG) * 2.0f * 0.25f;
    }
}

extern "C" void kernel_launch(void* const* d_in, const int* in_sizes, int n_in,
                              void* d_out, int out_size, void* d_ws, size_t ws_size,
                              hipStream_t stream) {
    const float* v1   = (const float*)d_in[0];
    const float* v2   = (const float*)d_in[1];
    const float* img  = (const float*)d_in[2];
    const int*   negh = (const int*)d_in[3];
    const int*   negw = (const int*)d_in[4];
    float* out = (float*)d_out;
    float* ws  = (float*)d_ws;

    ushort* z2tb    = (ushort*)(ws + OFF_Z2T);
    float* n1map    = ws + OFF_N1MAP;
    float* imgt4    = ws + OFF_IMGT4;
    float* partial  = ws + OFF_PARTIAL;
    float* partial2 = ws + OFF_PART2;
    float* perb     = ws + OFF_PERB;

    hipLaunchKernelGGL(k_prep_z2, dim3(B * 64), dim3(256), 0, stream, v2, z2tb);
    hipLaunchKernelGGL(k_prep_z1, dim3(B * 16), dim3(256), 0, stream, v1, img, n1map, imgt4);
    hipLaunchKernelGGL(k_main, dim3(B * NCHUNK), dim3(256), 0, stream,
                       v1, negh, negw, z2tb, n1map, imgt4, partial);
    hipLaunchKernelGGL(k_reduce1, dim3(B * NGRP), dim3(256), 0, stream, partial, partial2);
    hipLaunchKernelGGL(k_reduce2, dim3(B), dim3(256), 0, stream, partial2, n1map, perb);
    hipLaunchKernelGGL(k_final, dim3(1), dim3(64), 0, stream, perb, out);
}

// Round 5
// 60.774 us; speedup vs baseline: 4.0913x; 1.0289x over previous
//
#include <hip/hip_runtime.h>
#include <math.h>

typedef unsigned short ushort;
typedef unsigned int uint;

#define B 4
#define C 64
#define H 64
#define W 64
#define HW 4096
#define NEG 256
#define CHUNK_P 8
#define NCHUNK (HW / CHUNK_P)   // 512
#define NGRP 16
#define CHPG (NCHUNK / NGRP)    // 32

// ---------------- ws layout (float units) ----------------
// z2th   : [B][HW][64] f16 (column pre-normalized) = B*HW*32 floats
// n1map  : [B][HW]
// imgt4  : [HW][4]
// partial: [B][NCHUNK][NEG]
// partial2:[B][NGRP][NEG]
// perb   : [B][3]
#define OFF_Z2T     0
#define OFF_N1MAP   (OFF_Z2T + B*HW*32)
#define OFF_IMGT4   (OFF_N1MAP + B*HW)
#define OFF_PARTIAL (OFF_IMGT4 + HW*4)
#define OFF_PART2   (OFF_PARTIAL + B*NCHUNK*NEG)
#define OFF_PERB    (OFF_PART2 + B*NGRP*NEG)

typedef _Float16 h2_t __attribute__((ext_vector_type(2)));

__device__ __forceinline__ uint packf16(float a, float b) {
    _Float16 lo = (_Float16)a;
    _Float16 hi = (_Float16)b;
    return (uint)__builtin_bit_cast(unsigned short, lo) |
           ((uint)__builtin_bit_cast(unsigned short, hi) << 16);
}

__device__ __forceinline__ float dot2(uint a, uint b, float c) {
#if __has_builtin(__builtin_amdgcn_fdot2)
    return __builtin_amdgcn_fdot2(__builtin_bit_cast(h2_t, a),
                                  __builtin_bit_cast(h2_t, b), c, false);
#else
    h2_t x = __builtin_bit_cast(h2_t, a);
    h2_t y = __builtin_bit_cast(h2_t, b);
    return c + (float)x[0] * (float)y[0] + (float)x[1] * (float)y[1];
#endif
}

// Transpose views_2 (C,HW) -> z2th (HW,C) f16, columns pre-divided by their norm.
__global__ __launch_bounds__(256) void k_prep_z2(const float* __restrict__ v2,
                                                 ushort* __restrict__ z2th) {
    __shared__ float tile[64][65];
    __shared__ float npart[4][64];
    __shared__ float ninv[64];
    int b  = blockIdx.x >> 6;          // 64 tiles per item
    int q0 = (blockIdx.x & 63) * 64;
    int t  = threadIdx.x;
    int qq = t & 63;
    int cg = t >> 6;
    const float* src = v2 + (size_t)b * C * HW;
    float acc = 0.f;
#pragma unroll
    for (int r = 0; r < 16; ++r) {
        int c = cg * 16 + r;
        float v = src[(size_t)c * HW + q0 + qq];
        tile[c][qq] = v;
        acc += v * v;
    }
    npart[cg][qq] = acc;
    __syncthreads();
    if (t < 64) {
        float s = npart[0][t] + npart[1][t] + npart[2][t] + npart[3][t];
        ninv[t] = 1.0f / fmaxf(sqrtf(s), 1e-8f);
    }
    __syncthreads();
    int qw = t >> 2;
    int c0 = (t & 3) * 16;             // channel base (16 channels per thread)
    float inv = ninv[qw];
    uint us[8];
#pragma unroll
    for (int j = 0; j < 8; ++j)
        us[j] = packf16(tile[c0 + 2*j][qw] * inv, tile[c0 + 2*j + 1][qw] * inv);
    uint4* dst = (uint4*)(z2th + ((size_t)(b * HW + q0 + qw)) * 64 + c0);
    dst[0] = make_uint4(us[0], us[1], us[2], us[3]);
    dst[1] = make_uint4(us[4], us[5], us[6], us[7]);
}

// n1map (per-pixel norm of views_1) + img as float4 table.
__global__ __launch_bounds__(256) void k_prep_z1(const float* __restrict__ v1,
                                                 const float* __restrict__ img,
                                                 float* __restrict__ n1map,
                                                 float* __restrict__ imgt4) {
    int b = blockIdx.x >> 4;
    int q = (blockIdx.x & 15) * 256 + threadIdx.x;
    const float* src = v1 + (size_t)b * C * HW + q;
    float acc = 0.f;
#pragma unroll 8
    for (int c = 0; c < C; ++c) {
        float v = src[(size_t)c * HW];
        acc += v * v;
    }
    n1map[b * HW + q] = sqrtf(acc);
    if (b == 0) {
        float4 ip = make_float4(img[q], img[HW + q], img[2 * HW + q], 0.f);
        *(float4*)(imgt4 + q * 4) = ip;
    }
}

// Main: block = (b, 8 pixels). Phase A: q/wgt per (pp,k) into LDS (t=k).
// Phase B: 4-lane cooperative f16 column gather; v_dot2_f32_f16 + shfl reduce.
__global__ __launch_bounds__(256) void k_main(const float* __restrict__ v1,
                                              const int* __restrict__ negh,
                                              const int* __restrict__ negw,
                                              const ushort* __restrict__ z2th,
                                              const float* __restrict__ n1map,
                                              const float* __restrict__ imgt4,
                                              float* __restrict__ partial) {
    __shared__ __align__(16) uint z1p[CHUNK_P][36];    // packed f16 pairs; stride 144B (16B-mult)
    __shared__ float4 imgps[CHUNK_P];
    __shared__ int   q_lds[CHUNK_P][NEG];
    __shared__ float w_lds[CHUNK_P][NEG];
    int b     = blockIdx.x >> 9;       // NCHUNK = 512
    int chunk = blockIdx.x & 511;
    int p0    = chunk * CHUNK_P;
    int t     = threadIdx.x;

    {   // stage z1 columns, normalized + packed f16: z1p[pp][c2] = {v[2c2], v[2c2+1]} / n1
        int c2 = t >> 3;               // 0..31
        int pp = t & 7;
        const float* srcb = v1 + (size_t)b * C * HW;
        float inv = 1.0f / fmaxf(n1map[b * HW + p0 + pp], 1e-8f);
        float a0 = srcb[(size_t)(2 * c2)     * HW + p0 + pp] * inv;
        float a1 = srcb[(size_t)(2 * c2 + 1) * HW + p0 + pp] * inv;
        z1p[pp][c2] = packf16(a0, a1);
    }
    if (t < CHUNK_P) imgps[t] = *(const float4*)(imgt4 + (p0 + t) * 4);
    __syncthreads();

    const float inv_max_euc = 1.0f / sqrtf((float)((H - 1) * (H - 1) + (W - 1) * (W - 1)));
    const float inv_sqrt3   = 0.57735026919f;
    const int* nh = negh + ((size_t)b * HW + p0) * NEG + t;
    const int* nw = negw + ((size_t)b * HW + p0) * NEG + t;

    // Phase A: thread t = k index
#pragma unroll
    for (int pp = 0; pp < CHUNK_P; ++pp) {
        int p = p0 + pp;
        int ih = nh[pp * NEG];
        int iw = nw[pp * NEG];
        int qv = (ih << 6) + iw;
        float dh = (float)(p >> 6) - (float)ih;
        float dw = (float)(p & 63) - (float)iw;
        float euc = sqrtf(dh * dh + dw * dw) * inv_max_euc;
        float4 iq = *(const float4*)(imgt4 + qv * 4);
        float4 ip = imgps[pp];
        float dr = ip.x - iq.x, dg = ip.y - iq.y, db = ip.z - iq.z;
        float rgb = sqrtf(dr * dr + dg * dg + db * db) * inv_sqrt3;
        q_lds[pp][t] = qv;
        w_lds[pp][t] = 0.8f * euc + 0.2f * rgb;
    }
    __syncthreads();

    // Phase B: 4 lanes per column, g fully unrolled for MLP
    int c4 = t & 3;
    int kk = t >> 2;                   // 0..63 across block
    const ushort* z2b = z2th + (size_t)b * HW * 64;
    float acc = 0.f;
#pragma unroll 1
    for (int pp = 0; pp < CHUNK_P; ++pp) {
        const uint4* z1c = (const uint4*)(&z1p[pp][0]);
        uint4 a0 = z1c[c4];            // channels 8c4 .. 8c4+7
        uint4 a1 = z1c[4 + c4];        // channels 32+8c4 .. +7
#pragma unroll
        for (int g = 0; g < 4; ++g) {
            int kq = (g << 6) + kk;
            int qv = q_lds[pp][kq];
            float wv = w_lds[pp][kq];
            const uint4* col = (const uint4*)(z2b + (size_t)qv * 64);
            uint4 A  = col[c4];        // 16 B: channels 8c4..8c4+7
            uint4 Bv = col[4 + c4];    // channels 32+8c4..+7
            float dot = 0.f;
            dot = dot2(A.x,  a0.x, dot);
            dot = dot2(A.y,  a0.y, dot);
            dot = dot2(A.z,  a0.z, dot);
            dot = dot2(A.w,  a0.w, dot);
            dot = dot2(Bv.x, a1.x, dot);
            dot = dot2(Bv.y, a1.y, dot);
            dot = dot2(Bv.z, a1.z, dot);
            dot = dot2(Bv.w, a1.w, dot);
            dot += __shfl_xor(dot, 1);
            dot += __shfl_xor(dot, 2);
            float s = fminf(fabsf(dot * wv), 1.0f);
            acc += (g == c4) ? s : 0.f;
        }
    }
    partial[((size_t)b * NCHUNK + chunk) * NEG + (c4 << 6) + kk] = acc;
}

// Stage-1 reduce: sum 32 chunks per group.
__global__ __launch_bounds__(256) void k_reduce1(const float* __restrict__ partial,
                                                 float* __restrict__ partial2) {
    int b = blockIdx.x >> 4;
    int g = blockIdx.x & 15;
    int t = threadIdx.x;
    float s = 0.f;
#pragma unroll 4
    for (int ch = 0; ch < CHPG; ++ch)
        s += partial[((size_t)b * NCHUNK + g * CHPG + ch) * NEG + t];
    partial2[((size_t)b * NGRP + g) * NEG + t] = s;
}

// Stage-2: per-item sneg[k], log terms, s0, bce.
__global__ __launch_bounds__(256) void k_reduce2(const float* __restrict__ partial2,
                                                 const float* __restrict__ n1map,
                                                 float* __restrict__ perb) {
    __shared__ float red[256];
    int b = blockIdx.x;
    int t = threadIdx.x;
    float s = 0.f;
#pragma unroll
    for (int g = 0; g < NGRP; ++g)
        s += partial2[((size_t)b * NGRP + g) * NEG + t];
    float sneg = s * (1.0f / HW) * 0.5f;
    float l1m  = fmaxf(logf(1.0f - sneg), -100.0f);
    float ss = 0.f;
#pragma unroll
    for (int j = 0; j < HW / 256; ++j) {
        float n1 = n1map[b * HW + j * 256 + t];
        float n1sq = n1 * n1;
        ss += fminf(n1sq / fmaxf(n1sq, 1e-8f), 1.0f);
    }
    float snegsum, l1msum, sssum;
    red[t] = sneg; __syncthreads();
    for (int sft = 128; sft > 0; sft >>= 1) { if (t < sft) red[t] += red[t + sft]; __syncthreads(); }
    snegsum = red[0]; __syncthreads();
    red[t] = l1m; __syncthreads();
    for (int sft = 128; sft > 0; sft >>= 1) { if (t < sft) red[t] += red[t + sft]; __syncthreads(); }
    l1msum = red[0]; __syncthreads();
    red[t] = ss; __syncthreads();
    for (int sft = 128; sft > 0; sft >>= 1) { if (t < sft) red[t] += red[t + sft]; __syncthreads(); }
    sssum = red[0];
    if (t == 0) {
        float s0  = sssum * (1.0f / HW);
        float bce = -(fmaxf(logf(s0), -100.0f) + l1msum) * (1.0f / (NEG + 1));
        perb[b * 3 + 0] = bce;
        perb[b * 3 + 1] = s0;
        perb[b * 3 + 2] = snegsum;
    }
}

__global__ void k_final(const float* __restrict__ perb, float* __restrict__ out) {
    if (threadIdx.x == 0 && blockIdx.x == 0) {
        float bsum = 0.f, s0sum = 0.f, snegsum = 0.f;
        for (int b = 0; b < B; ++b) {
            bsum    += perb[b * 3 + 0];
            s0sum   += perb[b * 3 + 1];
            snegsum += perb[b * 3 + 2];
        }
        out[0] = bsum * 0.25f;
        out[1] = s0sum * 0.25f;
        out[2] = snegsum * (1.0f / NEG) * 2.0f * 0.25f;
    }
}

extern "C" void kernel_launch(void* const* d_in, const int* in_sizes, int n_in,
                              void* d_out, int out_size, void* d_ws, size_t ws_size,
                              hipStream_t stream) {
    const float* v1   = (const float*)d_in[0];
    const float* v2   = (const float*)d_in[1];
    const float* img  = (const float*)d_in[2];
    const int*   negh = (const int*)d_in[3];
    const int*   negw = (const int*)d_in[4];
    float* out = (float*)d_out;
    float* ws  = (float*)d_ws;

    ushort* z2th    = (ushort*)(ws + OFF_Z2T);
    float* n1map    = ws + OFF_N1MAP;
    float* imgt4    = ws + OFF_IMGT4;
    float* partial  = ws + OFF_PARTIAL;
    float* partial2 = ws + OFF_PART2;
    float* perb     = ws + OFF_PERB;

    hipLaunchKernelGGL(k_prep_z2, dim3(B * 64), dim3(256), 0, stream, v2, z2th);
    hipLaunchKernelGGL(k_prep_z1, dim3(B * 16), dim3(256), 0, stream, v1, img, n1map, imgt4);
    hipLaunchKernelGGL(k_main, dim3(B * NCHUNK), dim3(256), 0, stream,
                       v1, negh, negw, z2th, n1map, imgt4, partial);
    hipLaunchKernelGGL(k_reduce1, dim3(B * NGRP), dim3(256), 0, stream, partial, partial2);
    hipLaunchKernelGGL(k_reduce2, dim3(B), dim3(256), 0, stream, partial2, n1map, perb);
    hipLaunchKernelGGL(k_final, dim3(1), dim3(64), 0, stream, perb, out);
}